// Round 1
// baseline (929.388 us; speedup 1.0000x reference)
//
#include <hip/hip_runtime.h>
#include <stdint.h>

#define D_MODEL 2048
#define NHEAD   16
#define DHEAD   128
#define BATCH   4
#define SEQ     2048
#define MROWS   (BATCH*SEQ)          // 8192
#define WELEMS  (D_MODEL*D_MODEL)    // 4194304

typedef __attribute__((ext_vector_type(4))) float          f32x4;
typedef __attribute__((ext_vector_type(8))) short          s16x8;
typedef __attribute__((ext_vector_type(4))) unsigned short u16x4;

// ---------- helpers ----------
__device__ __forceinline__ unsigned short f2bf(float f) {
  union { float f; uint32_t u; } v; v.f = f;
  uint32_t r = v.u + 0x7fffu + ((v.u >> 16) & 1u);   // RNE
  return (unsigned short)(r >> 16);
}

__device__ __forceinline__ void load_lds16(const void* g, void* l) {
  // LDS dest is wave-uniform base + lane*16 (HW semantics); global src per-lane.
  __builtin_amdgcn_global_load_lds(
      (__attribute__((address_space(1))) void*)(g),
      (__attribute__((address_space(3))) void*)(l), 16, 0, 0);
}

__device__ __forceinline__ float gamma_of(const double* sums, int gidx) {
  double gs = sums[gidx] * (1.0 / (double)WELEMS);
  if (gs < 1e-5) gs = 1e-5;
  return (float)gs;
}

// ---------- abs-mean reduction (fp64 accumulate, 4 weights) ----------
__global__ __launch_bounds__(256) void absmean_kernel(
    const float* __restrict__ w0, const float* __restrict__ w1,
    const float* __restrict__ w2, const float* __restrict__ w3,
    double* __restrict__ sums) {
  const float* w = blockIdx.y == 0 ? w0 : blockIdx.y == 1 ? w1
                 : blockIdx.y == 2 ? w2 : w3;
  double acc = 0.0;
  const int stride = gridDim.x * blockDim.x;
  for (int i = blockIdx.x * blockDim.x + threadIdx.x; i < WELEMS / 4; i += stride) {
    float4 v = ((const float4*)w)[i];
    acc += (double)fabsf(v.x) + (double)fabsf(v.y) +
           (double)fabsf(v.z) + (double)fabsf(v.w);
  }
  acc += __shfl_xor(acc, 1);  acc += __shfl_xor(acc, 2);  acc += __shfl_xor(acc, 4);
  acc += __shfl_xor(acc, 8);  acc += __shfl_xor(acc, 16); acc += __shfl_xor(acc, 32);
  __shared__ double wsum[4];
  const int lane = threadIdx.x & 63, wave = threadIdx.x >> 6;
  if (lane == 0) wsum[wave] = acc;
  __syncthreads();
  if (threadIdx.x == 0)
    atomicAdd(&sums[blockIdx.y], wsum[0] + wsum[1] + wsum[2] + wsum[3]);
}

// ---------- ternary quantize -> bf16 bits ----------
__global__ __launch_bounds__(256) void quant_kernel(
    const float* __restrict__ wsrc, unsigned short* __restrict__ wt,
    const double* __restrict__ sums, int gidx) {
  const float gf = gamma_of(sums, gidx);
  const int i = blockIdx.x * 256 + threadIdx.x;
  float4 v = ((const float4*)wsrc)[i];
  u16x4 r;
  r[0] = f2bf(fminf(1.f, fmaxf(-1.f, rintf(v.x / gf))));
  r[1] = f2bf(fminf(1.f, fmaxf(-1.f, rintf(v.y / gf))));
  r[2] = f2bf(fminf(1.f, fmaxf(-1.f, rintf(v.z / gf))));
  r[3] = f2bf(fminf(1.f, fmaxf(-1.f, rintf(v.w / gf))));
  ((u16x4*)wt)[i] = r;
}

// ---------- f32 -> bf16 convert ----------
__global__ __launch_bounds__(256) void cvt_bf16_kernel(
    const float* __restrict__ x, unsigned short* __restrict__ xb) {
  const int i = blockIdx.x * 256 + threadIdx.x;
  float4 v = ((const float4*)x)[i];
  u16x4 r;
  r[0] = f2bf(v.x); r[1] = f2bf(v.y); r[2] = f2bf(v.z); r[3] = f2bf(v.w);
  ((u16x4*)xb)[i] = r;
}

// ---------- GEMM: C = (A @ Bt^T) * gamma  (m97 structure: 128x128, BK=32) ----------
// A: MROWS x 2048 bf16-bits row-major. Bt: 2048 x 2048 bf16-bits row-major (= W).
// MODE 0: bf16 out (row,col). MODE 1: bf16 out transposed to (b,h,d,t). MODE 2: f32 out.
template <int MODE>
__global__ __launch_bounds__(256) void gemm_bt_kernel(
    const unsigned short* __restrict__ A,
    const unsigned short* __restrict__ Bt,
    void* __restrict__ out,
    const double* __restrict__ sums, int gidx) {
  constexpr int K = D_MODEL;
  __shared__ unsigned short As[128 * 32];   // [row][32k] 64B rows, linear
  __shared__ unsigned short Bs[128 * 32];
  const int tid = threadIdx.x, lane = tid & 63, wave = tid >> 6;
  const int g = lane >> 4, r15 = lane & 15;
  const int wm = wave >> 1, wn = wave & 1;
  const int rowBase = blockIdx.y * 128, colBase = blockIdx.x * 128;

  f32x4 acc[4][4] = {};

  // staging slot: o = rnd*4096 + wave*1024 + lane*16 bytes; row=o>>6, k8=(o>>4)&3
  const int o0 = wave * 1024 + lane * 16;
  const int o1 = 4096 + wave * 1024 + lane * 16;
  const unsigned short* Ap0 = A  + (size_t)(rowBase + (o0 >> 6)) * K + ((o0 >> 4) & 3) * 8;
  const unsigned short* Ap1 = A  + (size_t)(rowBase + (o1 >> 6)) * K + ((o1 >> 4) & 3) * 8;
  const unsigned short* Bp0 = Bt + (size_t)(colBase + (o0 >> 6)) * K + ((o0 >> 4) & 3) * 8;
  const unsigned short* Bp1 = Bt + (size_t)(colBase + (o1 >> 6)) * K + ((o1 >> 4) & 3) * 8;
  char* AsB = (char*)As; char* BsB = (char*)Bs;

  for (int kt = 0; kt < K; kt += 32) {
    load_lds16(Ap0 + kt, AsB + wave * 1024);
    load_lds16(Ap1 + kt, AsB + 4096 + wave * 1024);
    load_lds16(Bp0 + kt, BsB + wave * 1024);
    load_lds16(Bp1 + kt, BsB + 4096 + wave * 1024);
    __syncthreads();
    s16x8 a[4], b[4];
#pragma unroll
    for (int m = 0; m < 4; ++m)
      a[m] = *(const s16x8*)(AsB + (wm * 64 + m * 16 + r15) * 64 + g * 16);
#pragma unroll
    for (int n = 0; n < 4; ++n)
      b[n] = *(const s16x8*)(BsB + (wn * 64 + n * 16 + r15) * 64 + g * 16);
#pragma unroll
    for (int m = 0; m < 4; ++m)
#pragma unroll
      for (int n = 0; n < 4; ++n)
        acc[m][n] = __builtin_amdgcn_mfma_f32_16x16x32_bf16(a[m], b[n], acc[m][n], 0, 0, 0);
    __syncthreads();
  }

  const float scale = gamma_of(sums, gidx);
#pragma unroll
  for (int m = 0; m < 4; ++m) {
    const int row0 = rowBase + wm * 64 + m * 16 + g * 4;   // C/D: row=(l>>4)*4+j
#pragma unroll
    for (int n = 0; n < 4; ++n) {
      const int col = colBase + wn * 64 + n * 16 + r15;    // C/D: col=l&15
      if constexpr (MODE == 2) {
        float* op = (float*)out;
#pragma unroll
        for (int j = 0; j < 4; ++j)
          op[(size_t)(row0 + j) * D_MODEL + col] = acc[m][n][j] * scale;
      } else if constexpr (MODE == 0) {
        unsigned short* op = (unsigned short*)out;
#pragma unroll
        for (int j = 0; j < 4; ++j)
          op[(size_t)(row0 + j) * D_MODEL + col] = f2bf(acc[m][n][j] * scale);
      } else {  // MODE 1: write V^T laid out (b, h, d, t); 4 j's are contiguous t
        unsigned short* op = (unsigned short*)out;
        const int bb = row0 >> 11, t = row0 & 2047;
        const int hh = col >> 7,  d = col & 127;
        u16x4 r;
#pragma unroll
        for (int j = 0; j < 4; ++j) r[j] = f2bf(acc[m][n][j] * scale);
        *(u16x4*)(op + (((size_t)bb * NHEAD + hh) * DHEAD + d) * SEQ + t) = r;
      }
    }
  }
}

// ---------- causal flash attention ----------
// q,k: (B*T, 2048) bf16 (gammas already folded). vt: (B,H,128,T) bf16. out: (B*T,2048) bf16.
// Block = (b, h, 64 q-rows); 4 waves x 16 q-rows. KV-tile = 64.
// LDS tiles use XOR swizzle byte^=((row&7)<<4), applied to the GLOBAL source on staging
// (linear LDS dest, rule #21) and to the address on every ds_read.
__global__ __launch_bounds__(256) void attn_kernel(
    const unsigned short* __restrict__ qg,
    const unsigned short* __restrict__ kg,
    const unsigned short* __restrict__ vtg,
    unsigned short* __restrict__ og) {
  __shared__ unsigned short Ks[64 * 128];    // [key][d]  256B rows
  __shared__ unsigned short Vts[128 * 64];   // [d][kv]   128B rows
  __shared__ unsigned short Ps[4][1024];     // per-wave [q16][kv64] 128B rows

  const int tid = threadIdx.x, lane = tid & 63, wave = tid >> 6;
  const int g = lane >> 4, r15 = lane & 15;
  const int qt = blockIdx.x, h = blockIdx.y, b = blockIdx.z;
  const float scale = 0.088388347648318447f;  // 1/sqrt(128); gq*gk folded upstream

  // Q fragments (A-layout: row=l&15, k=(l>>4)*8), hoisted for the whole block
  s16x8 qf[4];
  {
    const unsigned short* qbase =
        qg + (size_t)(b * SEQ + qt * 64 + wave * 16 + r15) * D_MODEL + h * DHEAD;
#pragma unroll
    for (int c = 0; c < 4; ++c) qf[c] = *(const s16x8*)(qbase + c * 32 + g * 8);
  }

  f32x4 oacc[8] = {};
  float mr[4], lr[4];
#pragma unroll
  for (int j = 0; j < 4; ++j) { mr[j] = -1e30f; lr[j] = 0.f; }

  char* KsB = (char*)Ks; char* VtsB = (char*)Vts; char* PsB = (char*)(Ps[wave]);

  const int nt = qt + 1;
  for (int t = 0; t < nt; ++t) {
    // ---- stage K (16KB) and Vt (16KB): linear LDS, pre-swizzled global source
#pragma unroll
    for (int rnd = 0; rnd < 4; ++rnd) {
      const int ob = rnd * 4096 + wave * 1024 + lane * 16;
      const int krow = ob >> 8;
      const int ksrc = (ob & 255) ^ ((krow & 7) << 4);
      load_lds16(kg + (size_t)(b * SEQ + t * 64 + krow) * D_MODEL + h * DHEAD + (ksrc >> 1),
                 KsB + rnd * 4096 + wave * 1024);
      const int drow = ob >> 7;
      const int vsrc = (ob & 127) ^ ((drow & 7) << 4);
      load_lds16(vtg + ((size_t)(b * NHEAD + h) * DHEAD + drow) * SEQ + t * 64 + (vsrc >> 1),
                 VtsB + rnd * 4096 + wave * 1024);
    }
    __syncthreads();

    // ---- S = Q K^T  (16 q-rows x 64 keys)
    f32x4 s[4] = {};
#pragma unroll
    for (int c = 0; c < 4; ++c) {
#pragma unroll
      for (int n = 0; n < 4; ++n) {
        const int key = n * 16 + r15;
        const int baddr = ((key << 8) + (c << 6) + (g << 4)) ^ ((key & 7) << 4);
        s16x8 kf = *(const s16x8*)(KsB + baddr);
        s[n] = __builtin_amdgcn_mfma_f32_16x16x32_bf16(qf[c], kf, s[n], 0, 0, 0);
      }
    }

    // ---- scale + causal mask + row max  (C/D: row q=g*4+j, col key=n*16+r15)
    const int q0 = qt * 64 + wave * 16 + g * 4;
    const int k0 = t * 64 + r15;
    float pm[4];
#pragma unroll
    for (int j = 0; j < 4; ++j) pm[j] = -1e30f;
#pragma unroll
    for (int n = 0; n < 4; ++n)
#pragma unroll
      for (int j = 0; j < 4; ++j) {
        float sv = s[n][j] * scale;
        if (k0 + n * 16 > q0 + j) sv = -1e30f;
        s[n][j] = sv;
        pm[j] = fmaxf(pm[j], sv);
      }
#pragma unroll
    for (int j = 0; j < 4; ++j) {
      pm[j] = fmaxf(pm[j], __shfl_xor(pm[j], 1));
      pm[j] = fmaxf(pm[j], __shfl_xor(pm[j], 2));
      pm[j] = fmaxf(pm[j], __shfl_xor(pm[j], 4));
      pm[j] = fmaxf(pm[j], __shfl_xor(pm[j], 8));
    }

    float rf[4], psum[4];
#pragma unroll
    for (int j = 0; j < 4; ++j) {
      const float mn = fmaxf(mr[j], pm[j]);
      rf[j] = __expf(mr[j] - mn);       // first tile: exp(-1e30) = 0
      mr[j] = mn;
      psum[j] = 0.f;
    }

    // ---- P = exp(S-m): accumulate row-sum, write bf16 P to swizzled per-wave LDS
#pragma unroll
    for (int n = 0; n < 4; ++n) {
      const int keyl = n * 16 + r15;
#pragma unroll
      for (int j = 0; j < 4; ++j) {
        const float p = __expf(s[n][j] - mr[j]);
        psum[j] += p;
        const int ql = g * 4 + j;
        const int baddr = ((ql << 7) + (keyl << 1)) ^ ((ql & 7) << 4);
        *(unsigned short*)(PsB + baddr) = f2bf(p);
      }
    }
#pragma unroll
    for (int j = 0; j < 4; ++j) {
      psum[j] += __shfl_xor(psum[j], 1);
      psum[j] += __shfl_xor(psum[j], 2);
      psum[j] += __shfl_xor(psum[j], 4);
      psum[j] += __shfl_xor(psum[j], 8);
      lr[j] = lr[j] * rf[j] + psum[j];
    }
#pragma unroll
    for (int n2 = 0; n2 < 8; ++n2)
#pragma unroll
      for (int j = 0; j < 4; ++j) oacc[n2][j] *= rf[j];

    // ---- O += P V   (A = P from per-wave LDS, B = Vt rows; in-wave LDS order is safe)
#pragma unroll
    for (int c2 = 0; c2 < 2; ++c2) {
      const int baddr_p = ((r15 << 7) + (c2 << 6) + (g << 4)) ^ ((r15 & 7) << 4);
      s16x8 pa = *(const s16x8*)(PsB + baddr_p);
#pragma unroll
      for (int n2 = 0; n2 < 8; ++n2) {
        const int d = n2 * 16 + r15;
        const int baddr_v = ((d << 7) + (c2 << 6) + (g << 4)) ^ ((d & 7) << 4);
        s16x8 vf = *(const s16x8*)(VtsB + baddr_v);
        oacc[n2] = __builtin_amdgcn_mfma_f32_16x16x32_bf16(pa, vf, oacc[n2], 0, 0, 0);
      }
    }
    __syncthreads();   // guard Ks/Vts for next tile
  }

  // ---- normalize + write (b,t,h,d)
  const unsigned short* dummy = qg; (void)dummy;
  unsigned short* obase =
      og + (size_t)(b * SEQ + qt * 64 + wave * 16 + g * 4) * D_MODEL + h * DHEAD;
#pragma unroll
  for (int n2 = 0; n2 < 8; ++n2) {
    const int d = n2 * 16 + r15;
#pragma unroll
    for (int j = 0; j < 4; ++j)
      obase[(size_t)j * D_MODEL + d] = f2bf(oacc[n2][j] / lr[j]);
  }
}

// ---------- launch ----------
extern "C" void kernel_launch(void* const* d_in, const int* in_sizes, int n_in,
                              void* d_out, int out_size, void* d_ws, size_t ws_size,
                              hipStream_t stream) {
  const float* x  = (const float*)d_in[0];
  const float* wq = (const float*)d_in[1];
  const float* wk = (const float*)d_in[2];
  const float* wv = (const float*)d_in[3];
  const float* wo = (const float*)d_in[4];
  float* out = (float*)d_out;

  char* ws = (char*)d_ws;
  double* sums = (double*)ws;
  size_t off = 256;
  unsigned short* wtern = (unsigned short*)(ws + off); off += (size_t)WELEMS * 2;        // 8 MB, reused x4
  unsigned short* xbf   = (unsigned short*)(ws + off); off += (size_t)MROWS * D_MODEL * 2; // 32 MB (later attn_out)
  unsigned short* qb    = (unsigned short*)(ws + off); off += (size_t)MROWS * D_MODEL * 2;
  unsigned short* kb    = (unsigned short*)(ws + off); off += (size_t)MROWS * D_MODEL * 2;
  unsigned short* vtb   = (unsigned short*)(ws + off); off += (size_t)MROWS * D_MODEL * 2;
  unsigned short* attn_out = xbf;  // x no longer needed after the 3 QKV GEMMs

  hipMemsetAsync(sums, 0, 4 * sizeof(double), stream);
  absmean_kernel<<<dim3(256, 4), 256, 0, stream>>>(wq, wk, wv, wo, sums);
  cvt_bf16_kernel<<<MROWS * D_MODEL / 4 / 256, 256, 0, stream>>>(x, xbf);

  const dim3 ggrid(D_MODEL / 128, MROWS / 128);
  quant_kernel<<<WELEMS / 4 / 256, 256, 0, stream>>>(wq, wtern, sums, 0);
  gemm_bt_kernel<0><<<ggrid, 256, 0, stream>>>(xbf, wtern, qb, sums, 0);
  quant_kernel<<<WELEMS / 4 / 256, 256, 0, stream>>>(wk, wtern, sums, 1);
  gemm_bt_kernel<0><<<ggrid, 256, 0, stream>>>(xbf, wtern, kb, sums, 1);
  quant_kernel<<<WELEMS / 4 / 256, 256, 0, stream>>>(wv, wtern, sums, 2);
  gemm_bt_kernel<1><<<ggrid, 256, 0, stream>>>(xbf, wtern, vtb, sums, 2);  // writes V^T (b,h,d,t)

  attn_kernel<<<dim3(SEQ / 64, NHEAD, BATCH), 256, 0, stream>>>(qb, kb, vtb, attn_out);

  quant_kernel<<<WELEMS / 4 / 256, 256, 0, stream>>>(wo, wtern, sums, 3);
  gemm_bt_kernel<2><<<ggrid, 256, 0, stream>>>(attn_out, wtern, out, sums, 3);
}